// Round 5
// baseline (322.555 us; speedup 1.0000x reference)
//
#include <hip/hip_runtime.h>
#include <hip/hip_bf16.h>

typedef __bf16 bf16x8 __attribute__((ext_vector_type(8)));
typedef __bf16 bf16x4 __attribute__((ext_vector_type(4)));
typedef float  f32x4  __attribute__((ext_vector_type(4)));

#define B_SZ    1024
#define COUT_SZ 512
#define K_SZ    32768   // G * CIN
#define TM 128
#define TN 128
#define BK 32

// async 16B/lane global -> LDS DMA; lane l lands at base + 16*l.
__device__ __forceinline__ void async_copy16(const void* g, void* l) {
  __builtin_amdgcn_global_load_lds(
      (const __attribute__((address_space(1))) unsigned int*)g,
      (__attribute__((address_space(3))) unsigned int*)l, 16, 0, 0);
}

// ---------------------------------------------------------------------------
// x fp32 -> bf16, persistent grid-stride (R4's fused one-shot blocks were
// latency-bound at 2.2 TB/s: 2 loads + 1 store then block exit). 2048 blocks
// x 8 iters gives deep per-thread ILP for the streaming path.
// ---------------------------------------------------------------------------
#define XCVT_BLOCKS 2048
__global__ __launch_bounds__(256) void xcvt_kernel(
    const float* __restrict__ x, __bf16* __restrict__ xb) {
  const size_t stride = (size_t)XCVT_BLOCKS * 256 * 8;
  size_t i = ((size_t)blockIdx.x * 256 + threadIdx.x) * 8;
#pragma unroll
  for (int it = 0; it < 4; ++it) {  // 2 chunks per iter -> 8 sweeps total
    f32x4 a0 = *(const f32x4*)(x + i);
    f32x4 c0 = *(const f32x4*)(x + i + 4);
    f32x4 a1 = *(const f32x4*)(x + i + stride);
    f32x4 c1 = *(const f32x4*)(x + i + stride + 4);
    bf16x8 o0, o1;
#pragma unroll
    for (int e = 0; e < 4; ++e) {
      o0[e] = (__bf16)a0[e]; o0[e + 4] = (__bf16)c0[e];
      o1[e] = (__bf16)a1[e]; o1[e + 4] = (__bf16)c1[e];
    }
    *(bf16x8*)(xb + i) = o0;
    *(bf16x8*)(xb + i + stride) = o1;
    i += 2 * stride;
  }
}

// ---------------------------------------------------------------------------
// W fp32 [k][o] -> Wt bf16 [o][k]. 64x64 tiles via fp32 LDS, pitch 65
// (<=2-way banks both phases, verified).
// ---------------------------------------------------------------------------
__global__ __launch_bounds__(256) void wtrans_kernel(
    const float* __restrict__ w, __bf16* __restrict__ wt) {
  __shared__ float t[64 * 65];
  const int kb = (blockIdx.x & 511) * 64;   // K_SZ/64 = 512
  const int ob = (blockIdx.x >> 9) * 64;
  const int tid = threadIdx.x;
  {  // load 64x64 fp32 tile, coalesced 256B rows
    const int o4 = (tid & 15) * 4;
    const int kr = tid >> 4;
    const float* src = w + (size_t)(kb + kr) * COUT_SZ + ob + o4;
#pragma unroll
    for (int i = 0; i < 4; ++i) {
      f32x4 v = *(const f32x4*)(src + (size_t)(16 * i) * COUT_SZ);
      *(f32x4*)&t[(kr + 16 * i) * 65 + o4] = v;
    }
  }
  __syncthreads();
  {  // transposed store, coalesced 128B rows of Wt
    const int k4 = (tid & 15) * 4;
    const int orow = tid >> 4;
#pragma unroll
    for (int j = 0; j < 4; ++j) {
      const int o = orow + 16 * j;
      bf16x4 p;
#pragma unroll
      for (int e = 0; e < 4; ++e) p[e] = (__bf16)t[(k4 + e) * 65 + o];
      *(bf16x4*)(wt + (size_t)(ob + o) * K_SZ + kb + k4) = p;
    }
  }
}

// ---------------------------------------------------------------------------
// Split-K GEMM — m97-verified structure: 128x128 tile, 256 thr (4 waves,
// each 64x64 = 4x4 frags of 16x16x32 bf16), BK=32, single-buffered 16 KB
// LDS, 2-barrier K-loop, 4 global_load_lds dwordx4 per block-iter.
// __launch_bounds__(256,4): 4 blocks/CU -> grid 1024 fully co-resident
// (R4's (256,3) left a 256-block trickle tail).
//
// LDS rows = 4 x 16B chunks; XOR swizzle phys = logical ^ (r&3), realized by
// permuting lanes' GLOBAL sources (DMA pins lane->LDS offset). Fragment
// reads spread uniformly over quad-bank groups.
//
// Block map lin = z + S*t: XCD = z%8 -> all 32 out-tiles of a z-group share
// one XCD's L2 (A-chunk x4, B-chunk x8 reuse, ~100 KB/iter working set).
// ---------------------------------------------------------------------------
__global__ __launch_bounds__(256, 4)
void gemm_kernel(const __bf16* __restrict__ xb, const __bf16* __restrict__ wt,
                 float* __restrict__ dst, int kchunk, int S) {
  __shared__ __bf16 As[TM * BK];  // 8 KB
  __shared__ __bf16 Bs[TN * BK];  // 8 KB

  const int lin = blockIdx.x;
  const int z = lin % S;
  const int t = lin / S;
  const int m0 = (t & 7) * TM;   // 8 m-tiles
  const int n0 = (t >> 3) * TN;  // 4 n-tiles
  const int tid  = threadIdx.x;
  const int w    = tid >> 6;
  const int lane = tid & 63;
  const int kbase = z * kchunk;

  // staging: wave w covers rows [w*32, w*32+32) of both tiles, 2 DMAs each.
  // lane l -> row l>>2, phys chunk l&3, source logical chunk (l&3)^(row&3).
  const int sRow = lane >> 2;
  const int sCh  = (lane & 3) ^ (sRow & 3);
  const __bf16* ag0 = xb + (size_t)(m0 + w * 32 + sRow) * K_SZ + kbase + sCh * 8;
  const __bf16* ag1 = xb + (size_t)(m0 + w * 32 + 16 + sRow) * K_SZ + kbase + sCh * 8;
  const __bf16* bg0 = wt + (size_t)(n0 + w * 32 + sRow) * K_SZ + kbase + sCh * 8;
  const __bf16* bg1 = wt + (size_t)(n0 + w * 32 + 16 + sRow) * K_SZ + kbase + sCh * 8;
  __bf16* aL0 = &As[(w * 32) * BK];
  __bf16* aL1 = &As[(w * 32 + 16) * BK];
  __bf16* bL0 = &Bs[(w * 32) * BK];
  __bf16* bL1 = &Bs[(w * 32 + 16) * BK];

  // fragment geometry
  const int lm = lane & 15;
  const int q  = lane >> 4;
  const int wm = (w & 1) * 64;
  const int wn = (w >> 1) * 64;
  const int pc = q ^ (lm & 3);

  f32x4 acc[4][4];
#pragma unroll
  for (int i = 0; i < 4; ++i)
#pragma unroll
    for (int j = 0; j < 4; ++j)
      acc[i][j] = (f32x4){0.f, 0.f, 0.f, 0.f};

  const int niter = kchunk / BK;
  for (int it = 0; it < niter; ++it) {
    async_copy16(ag0, aL0);
    async_copy16(ag1, aL1);
    async_copy16(bg0, bL0);
    async_copy16(bg1, bL1);
    ag0 += BK; ag1 += BK; bg0 += BK; bg1 += BK;
    __syncthreads();  // drain DMA -> tiles valid

    bf16x8 af[4], bfr[4];
#pragma unroll
    for (int i = 0; i < 4; ++i)
      af[i] = *(const bf16x8*)&As[(wm + i * 16 + lm) * BK + pc * 8];
#pragma unroll
    for (int j = 0; j < 4; ++j)
      bfr[j] = *(const bf16x8*)&Bs[(wn + j * 16 + lm) * BK + pc * 8];

#pragma unroll
    for (int i = 0; i < 4; ++i)
#pragma unroll
      for (int j = 0; j < 4; ++j)
        acc[i][j] = __builtin_amdgcn_mfma_f32_16x16x32_bf16(af[i], bfr[j], acc[i][j], 0, 0, 0);

    __syncthreads();  // protect LDS from next staging
  }

  // epilogue: C/D layout col=lane&15, row=(lane>>4)*4+reg  [m89-verified]
  float* outp = dst + (size_t)z * (B_SZ * COUT_SZ)
              + (size_t)(m0 + wm + q * 4) * COUT_SZ + (n0 + wn + lm);
#pragma unroll
  for (int i = 0; i < 4; ++i) {
#pragma unroll
    for (int r = 0; r < 4; ++r) {
      float* o2 = outp + (size_t)(i * 16 + r) * COUT_SZ;
#pragma unroll
      for (int j = 0; j < 4; ++j)
        o2[j * 16] = acc[i][j][r];
    }
  }
}

// ---------------------------------------------------------------------------
// Reduce S partial slices + scale by 1/sqrt(512).
// ---------------------------------------------------------------------------
__global__ __launch_bounds__(256) void reduce_kernel(
    const float* __restrict__ p, float* __restrict__ out, int S, float scale) {
  const int i = (blockIdx.x * 256 + threadIdx.x) * 4;
  f32x4 s0 = (f32x4){0.f, 0.f, 0.f, 0.f};
  f32x4 s1 = (f32x4){0.f, 0.f, 0.f, 0.f};
  int zz = 0;
  for (; zz + 1 < S; zz += 2) {
    s0 = s0 + *(const f32x4*)(p + (size_t)zz * (B_SZ * COUT_SZ) + i);
    s1 = s1 + *(const f32x4*)(p + (size_t)(zz + 1) * (B_SZ * COUT_SZ) + i);
  }
  for (; zz < S; ++zz)
    s0 = s0 + *(const f32x4*)(p + (size_t)zz * (B_SZ * COUT_SZ) + i);
  s0 = (s0 + s1) * scale;
  *(f32x4*)(out + i) = s0;
}

extern "C" void kernel_launch(void* const* d_in, const int* in_sizes, int n_in,
                              void* d_out, int out_size, void* d_ws, size_t ws_size,
                              hipStream_t stream) {
  const float* x = (const float*)d_in[0];
  const float* w = (const float*)d_in[1];
  float* out = (float*)d_out;

  const size_t wtB    = (size_t)COUT_SZ * K_SZ * sizeof(__bf16);  // 33.5 MB
  const size_t xbB    = (size_t)B_SZ * K_SZ * sizeof(__bf16);     // 67 MB
  const size_t sliceB = (size_t)B_SZ * COUT_SZ * sizeof(float);   // 2 MB

  __bf16* wt = (__bf16*)d_ws;
  __bf16* xb = (__bf16*)((char*)d_ws + wtB);
  float* partials = (float*)((char*)d_ws + wtB + xbB);

  int S = 32;  // grid 1024 = 4 blocks/CU, fully co-resident; kchunk 1024
  while (S > 1 && wtB + xbB + (size_t)S * sliceB > ws_size) S >>= 1;
  if (wtB + xbB + sliceB > ws_size) { partials = out; S = 1; }  // last resort

  const float scale = 0.04419417382415922f;  // 1/sqrt(512)

  hipLaunchKernelGGL(xcvt_kernel, dim3(XCVT_BLOCKS), dim3(256), 0, stream, x, xb);
  hipLaunchKernelGGL(wtrans_kernel, dim3((K_SZ / 64) * (COUT_SZ / 64)), dim3(256),
                     0, stream, w, wt);
  hipLaunchKernelGGL(gemm_kernel, dim3(32 * S), dim3(256), 0, stream,
                     xb, wt, partials, K_SZ / S, S);
  hipLaunchKernelGGL(reduce_kernel, dim3(B_SZ * COUT_SZ / 1024), dim3(256), 0,
                     stream, partials, out, S, scale);
}

// Round 6
// 297.365 us; speedup vs baseline: 1.0847x; 1.0847x over previous
//
#include <hip/hip_runtime.h>
#include <hip/hip_bf16.h>

typedef __bf16 bf16x8 __attribute__((ext_vector_type(8)));
typedef __bf16 bf16x4 __attribute__((ext_vector_type(4)));
typedef float  f32x4  __attribute__((ext_vector_type(4)));

#define B_SZ    1024
#define COUT_SZ 512
#define K_SZ    32768   // G * CIN
#define TM 128
#define TN 128
#define BK 32
#define APITCH 36       // A-LDS row pitch in bf16 (72 B): writes & b64 frag
                        // reads both land at bank-depth 4 = wave64 floor

// async 16B/lane global -> LDS DMA; lane l lands at base + 16*l.
__device__ __forceinline__ void async_copy16(const void* g, void* l) {
  __builtin_amdgcn_global_load_lds(
      (const __attribute__((address_space(1))) unsigned int*)g,
      (__attribute__((address_space(3))) unsigned int*)l, 16, 0, 0);
}

// ---------------------------------------------------------------------------
// W fp32 [k][o] -> Wt bf16 [o][k]. 64x64 tiles via fp32 LDS, pitch 65
// (<=2-way banks both phases, verified).
// ---------------------------------------------------------------------------
__global__ __launch_bounds__(256) void wtrans_kernel(
    const float* __restrict__ w, __bf16* __restrict__ wt) {
  __shared__ float t[64 * 65];
  const int kb = (blockIdx.x & 511) * 64;   // K_SZ/64 = 512
  const int ob = (blockIdx.x >> 9) * 64;
  const int tid = threadIdx.x;
  {  // load 64x64 fp32 tile, coalesced 256B rows
    const int o4 = (tid & 15) * 4;
    const int kr = tid >> 4;
    const float* src = w + (size_t)(kb + kr) * COUT_SZ + ob + o4;
#pragma unroll
    for (int i = 0; i < 4; ++i) {
      f32x4 v = *(const f32x4*)(src + (size_t)(16 * i) * COUT_SZ);
      *(f32x4*)&t[(kr + 16 * i) * 65 + o4] = v;
    }
  }
  __syncthreads();
  {  // transposed store, coalesced 128B rows of Wt
    const int k4 = (tid & 15) * 4;
    const int orow = tid >> 4;
#pragma unroll
    for (int j = 0; j < 4; ++j) {
      const int o = orow + 16 * j;
      bf16x4 p;
#pragma unroll
      for (int e = 0; e < 4; ++e) p[e] = (__bf16)t[(k4 + e) * 65 + o];
      *(bf16x4*)(wt + (size_t)(ob + o) * K_SZ + kb + k4) = p;
    }
  }
}

// ---------------------------------------------------------------------------
// Split-K GEMM reading x fp32 DIRECTLY (no xcvt prepass):
// 128x128 tile, 256 thr (4 waves, 4x4 frags of 16x16x32 bf16), BK=32,
// 2-barrier K-loop. A staged by VALU: thread -> (row tid>>1, k-half tid&1),
// 4x f32x4 global loads -> cvt -> 4x ds_write_b64 into pitch-36 LDS. The A
// load latency overlaps the B-DMA latency already exposed at the barrier
// (inter-block overlap, 4 blocks/CU, hides both). B staged via
// global_load_lds with 16B-chunk XOR swizzle phys = logical ^ (row&3).
//
// Block map lin = z + S*t: XCD = z%8 -> all 32 out-tiles of a z-group share
// one XCD's L2 (A-chunk x4, B-chunk x8 reuse).
// Partials stored bf16 (halves reduce traffic; error budget checked).
// ---------------------------------------------------------------------------
__global__ __launch_bounds__(256, 4)
void gemm_kernel(const float* __restrict__ x, const __bf16* __restrict__ wt,
                 __bf16* __restrict__ dst, int kchunk, int S) {
  __shared__ __bf16 As[TM * APITCH];  // 9 KB
  __shared__ __bf16 Bs[TN * BK];      // 8 KB

  const int lin = blockIdx.x;
  const int z = lin % S;
  const int t = lin / S;
  const int m0 = (t & 7) * TM;   // 8 m-tiles
  const int n0 = (t >> 3) * TN;  // 4 n-tiles
  const int tid  = threadIdx.x;
  const int w    = tid >> 6;
  const int lane = tid & 63;
  const int kbase = z * kchunk;

  // A staging geometry: thread -> row tid>>1, k-half (tid&1)*16
  const int ar = tid >> 1;
  const int ah = tid & 1;
  const float* ag = x + (size_t)(m0 + ar) * K_SZ + kbase + ah * 16;
  __bf16* aw = &As[ar * APITCH + ah * 16];

  // B staging via DMA: lane l -> row l>>2, phys chunk l&3, logical (l&3)^(row&3)
  const int sRow = lane >> 2;
  const int sCh  = (lane & 3) ^ (sRow & 3);
  const __bf16* bg0 = wt + (size_t)(n0 + w * 32 + sRow) * K_SZ + kbase + sCh * 8;
  const __bf16* bg1 = wt + (size_t)(n0 + w * 32 + 16 + sRow) * K_SZ + kbase + sCh * 8;
  __bf16* bL0 = &Bs[(w * 32) * BK];
  __bf16* bL1 = &Bs[(w * 32 + 16) * BK];

  // fragment geometry
  const int lm = lane & 15;
  const int q  = lane >> 4;
  const int wm = (w & 1) * 64;
  const int wn = (w >> 1) * 64;
  const int pc = q ^ (lm & 3);  // B chunk swizzle at read

  f32x4 acc[4][4];
#pragma unroll
  for (int i = 0; i < 4; ++i)
#pragma unroll
    for (int j = 0; j < 4; ++j)
      acc[i][j] = (f32x4){0.f, 0.f, 0.f, 0.f};

  const int niter = kchunk / BK;
  for (int it = 0; it < niter; ++it) {
    // B: direct-to-LDS DMA (in flight until barrier)
    async_copy16(bg0, bL0);
    async_copy16(bg1, bL1);
    bg0 += BK; bg1 += BK;
    // A: fp32 load -> bf16 cvt -> LDS (latency overlaps the DMA drain)
    {
      f32x4 p0 = *(const f32x4*)(ag);
      f32x4 p1 = *(const f32x4*)(ag + 4);
      f32x4 p2 = *(const f32x4*)(ag + 8);
      f32x4 p3 = *(const f32x4*)(ag + 12);
      ag += BK;
      bf16x4 c0, c1, c2, c3;
#pragma unroll
      for (int e = 0; e < 4; ++e) {
        c0[e] = (__bf16)p0[e]; c1[e] = (__bf16)p1[e];
        c2[e] = (__bf16)p2[e]; c3[e] = (__bf16)p3[e];
      }
      *(bf16x4*)(aw)      = c0;
      *(bf16x4*)(aw + 4)  = c1;
      *(bf16x4*)(aw + 8)  = c2;
      *(bf16x4*)(aw + 12) = c3;
    }
    __syncthreads();  // drains DMA (vmcnt) + A writes (lgkm) -> tiles valid

    bf16x8 af[4], bfr[4];
#pragma unroll
    for (int i = 0; i < 4; ++i) {
      const __bf16* arow = &As[(wm + i * 16 + lm) * APITCH + q * 8];
      bf16x4 lo = *(const bf16x4*)arow;
      bf16x4 hi = *(const bf16x4*)(arow + 4);
      bf16x8 a;
#pragma unroll
      for (int e = 0; e < 4; ++e) { a[e] = lo[e]; a[e + 4] = hi[e]; }
      af[i] = a;
    }
#pragma unroll
    for (int j = 0; j < 4; ++j)
      bfr[j] = *(const bf16x8*)&Bs[(wn + j * 16 + lm) * BK + pc * 8];

#pragma unroll
    for (int i = 0; i < 4; ++i)
#pragma unroll
      for (int j = 0; j < 4; ++j)
        acc[i][j] = __builtin_amdgcn_mfma_f32_16x16x32_bf16(af[i], bfr[j], acc[i][j], 0, 0, 0);

    __syncthreads();  // protect LDS from next staging
  }

  // epilogue -> bf16 partials. C/D layout col=lane&15, row=(lane>>4)*4+reg.
  __bf16* outp = dst + (size_t)z * (B_SZ * COUT_SZ)
               + (size_t)(m0 + wm + q * 4) * COUT_SZ + (n0 + wn + lm);
#pragma unroll
  for (int i = 0; i < 4; ++i) {
#pragma unroll
    for (int r = 0; r < 4; ++r) {
      __bf16* o2 = outp + (size_t)(i * 16 + r) * COUT_SZ;
#pragma unroll
      for (int j = 0; j < 4; ++j)
        o2[j * 16] = (__bf16)acc[i][j][r];
    }
  }
}

// ---------------------------------------------------------------------------
// Reduce S bf16 partial slices (fp32 accumulate) + scale by 1/sqrt(512).
// ---------------------------------------------------------------------------
__global__ __launch_bounds__(256) void reduce_kernel(
    const __bf16* __restrict__ p, float* __restrict__ out, int S, float scale) {
  const size_t i = ((size_t)blockIdx.x * 256 + threadIdx.x) * 8;
  float s[8];
#pragma unroll
  for (int e = 0; e < 8; ++e) s[e] = 0.f;
  for (int zz = 0; zz < S; ++zz) {
    bf16x8 v = *(const bf16x8*)(p + (size_t)zz * (B_SZ * COUT_SZ) + i);
#pragma unroll
    for (int e = 0; e < 8; ++e) s[e] += (float)v[e];
  }
  f32x4 o0, o1;
#pragma unroll
  for (int e = 0; e < 4; ++e) { o0[e] = s[e] * scale; o1[e] = s[e + 4] * scale; }
  *(f32x4*)(out + i) = o0;
  *(f32x4*)(out + i + 4) = o1;
}

extern "C" void kernel_launch(void* const* d_in, const int* in_sizes, int n_in,
                              void* d_out, int out_size, void* d_ws, size_t ws_size,
                              hipStream_t stream) {
  const float* x = (const float*)d_in[0];
  const float* w = (const float*)d_in[1];
  float* out = (float*)d_out;

  const size_t wtB    = (size_t)COUT_SZ * K_SZ * sizeof(__bf16);   // 33.5 MB
  const size_t sliceB = (size_t)B_SZ * COUT_SZ * sizeof(__bf16);   // 1 MB

  __bf16* wt = (__bf16*)d_ws;
  __bf16* partials = (__bf16*)((char*)d_ws + wtB);

  int S = 32;  // grid 1024 = 4 blocks/CU fully co-resident; kchunk 1024
  while (S > 1 && wtB + (size_t)S * sliceB > ws_size) S >>= 1;

  const float scale = 0.04419417382415922f;  // 1/sqrt(512)

  hipLaunchKernelGGL(wtrans_kernel, dim3((K_SZ / 64) * (COUT_SZ / 64)), dim3(256),
                     0, stream, w, wt);
  hipLaunchKernelGGL(gemm_kernel, dim3(32 * S), dim3(256), 0, stream,
                     x, wt, partials, K_SZ / S, S);
  hipLaunchKernelGGL(reduce_kernel, dim3(B_SZ * COUT_SZ / (256 * 8)), dim3(256),
                     0, stream, partials, out, S, scale);
}